// Round 1
// baseline (112.939 us; speedup 1.0000x reference)
//
#include <hip/hip_runtime.h>
#include <hip/hip_bf16.h>

#define NBS 8
#define NT 32
#define NF 128
#define NDIN 64
#define NNH 8
#define NDOUT 64

typedef __bf16 bf16_t;
typedef __bf16 bf16x8 __attribute__((ext_vector_type(8)));
typedef float f32x4 __attribute__((ext_vector_type(4)));

// One block per (b,t). 512 threads = 8 waves; wave w owns output rows f in [16w,16w+16).
__global__ __launch_bounds__(512, 2)
void spatial_attn_kernel(const float* __restrict__ X,
                         const float* __restrict__ Wq,
                         const float* __restrict__ Wk,
                         const float* __restrict__ Wkey,
                         const float* __restrict__ U,
                         const float* __restrict__ AC,
                         const float* __restrict__ Alpha,
                         const float* __restrict__ Wo,
                         const float* __restrict__ Bias,
                         float* __restrict__ Out)
{
    const int blk  = blockIdx.x;
    const int b    = blk & 7;   // b fast -> same-t blocks land on different XCDs, share W[t] via L2/L3
    const int t    = blk >> 3;
    const int tid  = threadIdx.x;
    const int w    = tid >> 6;
    const int lane = tid & 63;

    // LDS: 130560 B total (< 160 KiB)
    __shared__ float  Xs[NF][NDIN + 1];     // 33280  X[b,t] tile fp32, +1 pad (phase-B broadcast reads)
    __shared__ bf16_t XT[NDIN][NF + 8];     // 17408  X^T bf16 (GEMM1 B operand), +8 pad -> 2-way banks
    __shared__ float  qT[16][NF];           // 8192   q[he][f]
    __shared__ float  kT[16][NF];           // 8192   k[he][f]
    __shared__ float  uT[2][NF];            // 1024   u[e][l]
    __shared__ bf16_t Pl[NF][NF + 8];       // 34816  probs[f][l] bf16 (GEMM1 A), +8 pad
    __shared__ bf16_t Vl[NF][72];           // 18432  vals_h[f][d] bf16 (GEMM2 A), stride 72
    __shared__ bf16_t WT[NDOUT][72];        // 9216   W[t,h-slab]^T [o][d] bf16 (GEMM2 B)

    // ---- phase 0: stage X[b,:,t,:] into Xs (f32) and XT (bf16 transposed) ----
    for (int i = tid; i < NF * NDIN / 4; i += 512) {
        const int f = i >> 4, d4 = (i & 15) << 2;
        const float4 v = *(const float4*)&X[(((size_t)b * NF + f) * NT + t) * NDIN + d4];
        Xs[f][d4 + 0] = v.x; Xs[f][d4 + 1] = v.y; Xs[f][d4 + 2] = v.z; Xs[f][d4 + 3] = v.w;
        XT[d4 + 0][f] = (bf16_t)v.x; XT[d4 + 1][f] = (bf16_t)v.y;
        XT[d4 + 2][f] = (bf16_t)v.z; XT[d4 + 3][f] = (bf16_t)v.w;
    }
    if (tid < 256) {
        const int l = tid >> 1, e = tid & 1;
        uT[e][l] = U[((size_t)t * NF + l) * 2 + e];
    }
    const float alpha_t = Alpha[t];
    const float wk00 = Wkey[t * 4 + 0], wk01 = Wkey[t * 4 + 1];
    const float wk10 = Wkey[t * 4 + 2], wk11 = Wkey[t * 4 + 3];

    __syncthreads();

    // ---- phase B: q/k projections. thread = (h=tid&7, f=tid>>3 + 64*pass) ----
    {
        const int h = tid & 7, fb = tid >> 3;
        for (int pass = 0; pass < 2; ++pass) {
            const int f = pass * 64 + fb;
            const float* wqp = Wq + ((size_t)t * NF + f) * (NDIN * 16) + h * 2;
            const float* wkp = Wk + ((size_t)t * NF + f) * (NDIN * 16) + h * 2;
            float q0 = 0.f, q1 = 0.f, k0 = 0.f, k1 = 0.f;
#pragma unroll 8
            for (int d = 0; d < NDIN; ++d) {
                const float x = Xs[f][d];
                const float2 a = *(const float2*)(wqp + (size_t)d * 16);
                const float2 c = *(const float2*)(wkp + (size_t)d * 16);
                q0 = fmaf(x, a.x, q0); q1 = fmaf(x, a.y, q1);
                k0 = fmaf(x, c.x, k0); k1 = fmaf(x, c.y, k1);
            }
            qT[2 * h + 0][f] = q0; qT[2 * h + 1][f] = q1;
            kT[2 * h + 0][f] = k0; kT[2 * h + 1][f] = k1;
        }
    }
    __syncthreads();

    // out accumulator: rows 16w..16w+15, cols nt*16 + (lane&15); row-in-tile = (lane>>4)*4+r
    f32x4 oacc[4] = { {0.f,0.f,0.f,0.f}, {0.f,0.f,0.f,0.f}, {0.f,0.f,0.f,0.f}, {0.f,0.f,0.f,0.f} };

    for (int h = 0; h < NNH; ++h) {
        // C1: stage W[t, h*64+d, o] transposed -> WT[o][d] (bf16)
        for (int i = tid; i < NDOUT * NDOUT; i += 512) {
            const int o = i & 63, d = i >> 6;
            WT[o][d] = (bf16_t)Wo[((size_t)t * 512 + h * 64 + d) * NDOUT + o];
        }
        // C2: scores + softmax -> Pl. wave handles its 16 f's, 2 at a time (ILP).
        {
            const float v0 = -alpha_t;
            const float v1 = 2.f * alpha_t * AC[t * NNH + h];
            const float* kr0 = kT[2 * h + 0];
            const float* kr1 = kT[2 * h + 1];
            const float* qr0 = qT[2 * h + 0];
            const float* qr1 = qT[2 * h + 1];
            // per-lane, f-independent values (l = lane and lane+64)
            const float ka0 = kr0[lane],      ka1 = kr1[lane];
            const float kb0 = kr0[lane + 64], kb1 = kr1[lane + 64];
            const float ua0 = uT[0][lane],    ua1 = uT[1][lane];
            const float ub0 = uT[0][lane + 64], ub1 = uT[1][lane + 64];
            const float la = (float)lane, lb = (float)(lane + 64);

            for (int i = 0; i < 8; ++i) {
                const int f1 = 16 * w + i, f2 = f1 + 8;
                const float q10 = qr0[f1], q11 = qr1[f1];
                const float q20 = qr0[f2], q21 = qr1[f2];
                const float kf10 = kr0[f1], kf11 = kr1[f1];
                const float kf20 = kr0[f2], kf21 = kr1[f2];
                // terms 2+4 collapse: sum_d (q_d+v_d)*(wk[d,0]*delta^2 + wk[d,1]*delta)
                const float c10 = (q10 + v0) * wk00 + (q11 + v1) * wk10;
                const float c11 = (q10 + v0) * wk01 + (q11 + v1) * wk11;
                const float c20 = (q20 + v0) * wk00 + (q21 + v1) * wk10;
                const float c21 = (q20 + v0) * wk01 + (q21 + v1) * wk11;
                const float d1a = la - (float)f1, d1b = lb - (float)f1;
                const float d2a = la - (float)f2, d2b = lb - (float)f2;
                float s1a = q10*ka0 + q11*ka1 + (c10*d1a + c11)*d1a + kf10*ua0 + kf11*ua1;
                float s1b = q10*kb0 + q11*kb1 + (c10*d1b + c11)*d1b + kf10*ub0 + kf11*ub1;
                float s2a = q20*ka0 + q21*ka1 + (c20*d2a + c21)*d2a + kf20*ua0 + kf21*ua1;
                float s2b = q20*kb0 + q21*kb1 + (c20*d2b + c21)*d2b + kf20*ub0 + kf21*ub1;
                float m1 = fmaxf(s1a, s1b), m2 = fmaxf(s2a, s2b);
#pragma unroll
                for (int off = 32; off > 0; off >>= 1) {
                    m1 = fmaxf(m1, __shfl_xor(m1, off));
                    m2 = fmaxf(m2, __shfl_xor(m2, off));
                }
                const float e1a = __expf(s1a - m1), e1b = __expf(s1b - m1);
                const float e2a = __expf(s2a - m2), e2b = __expf(s2b - m2);
                float t1 = e1a + e1b, t2 = e2a + e2b;
#pragma unroll
                for (int off = 32; off > 0; off >>= 1) {
                    t1 += __shfl_xor(t1, off);
                    t2 += __shfl_xor(t2, off);
                }
                const float r1 = 1.f / t1, r2 = 1.f / t2;
                Pl[f1][lane] = (bf16_t)(e1a * r1); Pl[f1][lane + 64] = (bf16_t)(e1b * r1);
                Pl[f2][lane] = (bf16_t)(e2a * r2); Pl[f2][lane + 64] = (bf16_t)(e2b * r2);
            }
        }
        __syncthreads();

        // C3+C4: GEMM1  vals_h[16x64 per wave] = P[16x128] @ X[128x64]  (MFMA 16x16x32 bf16)
        {
            f32x4 vacc[4] = { {0.f,0.f,0.f,0.f}, {0.f,0.f,0.f,0.f}, {0.f,0.f,0.f,0.f}, {0.f,0.f,0.f,0.f} };
            const int frow = 16 * w + (lane & 15);
            const int kg = (lane >> 4) << 3;
#pragma unroll
            for (int kt = 0; kt < 4; ++kt) {
                const bf16x8 a = *(const bf16x8*)&Pl[frow][kt * 32 + kg];
#pragma unroll
                for (int nt = 0; nt < 4; ++nt) {
                    const bf16x8 bb = *(const bf16x8*)&XT[nt * 16 + (lane & 15)][kt * 32 + kg];
                    vacc[nt] = __builtin_amdgcn_mfma_f32_16x16x32_bf16(a, bb, vacc[nt], 0, 0, 0);
                }
            }
            // D layout: col = lane&15, row = (lane>>4)*4 + r
            const int r0 = 16 * w + ((lane >> 4) << 2);
            const int c  = lane & 15;
#pragma unroll
            for (int nt = 0; nt < 4; ++nt)
#pragma unroll
                for (int r = 0; r < 4; ++r)
                    Vl[r0 + r][nt * 16 + c] = (bf16_t)vacc[nt][r];
        }
        __syncthreads();

        // C5: GEMM2  out[16x64 per wave] += Vl[16x64] @ Wslab[64x64]
        {
            const int frow = 16 * w + (lane & 15);
            const int kg = (lane >> 4) << 3;
#pragma unroll
            for (int kt = 0; kt < 2; ++kt) {
                const bf16x8 a = *(const bf16x8*)&Vl[frow][kt * 32 + kg];
#pragma unroll
                for (int nt = 0; nt < 4; ++nt) {
                    const bf16x8 bw = *(const bf16x8*)&WT[nt * 16 + (lane & 15)][kt * 32 + kg];
                    oacc[nt] = __builtin_amdgcn_mfma_f32_16x16x32_bf16(a, bw, oacc[nt], 0, 0, 0);
                }
            }
        }
        __syncthreads();
    }

    // ---- epilogue: out[b,f,t,o] = oacc + bias[f,t,o] ----
    {
        const int r0 = 16 * w + ((lane >> 4) << 2);
        const int c  = lane & 15;
#pragma unroll
        for (int nt = 0; nt < 4; ++nt) {
#pragma unroll
            for (int r = 0; r < 4; ++r) {
                const int f = r0 + r, o = nt * 16 + c;
                Out[(((size_t)b * NF + f) * NT + t) * NDOUT + o] =
                    oacc[nt][r] + Bias[((size_t)f * NT + t) * NDOUT + o];
            }
        }
    }
}

extern "C" void kernel_launch(void* const* d_in, const int* in_sizes, int n_in,
                              void* d_out, int out_size, void* d_ws, size_t ws_size,
                              hipStream_t stream) {
    (void)in_sizes; (void)n_in; (void)d_ws; (void)ws_size; (void)out_size;
    const float* X    = (const float*)d_in[0];
    const float* Wq   = (const float*)d_in[1];
    const float* Wk   = (const float*)d_in[2];
    const float* Wkey = (const float*)d_in[3];
    const float* U    = (const float*)d_in[4];
    const float* AC   = (const float*)d_in[5];
    const float* Al   = (const float*)d_in[6];
    // d_in[7] = R is analytically (delta^2, delta) and folded into the score formula
    const float* Wo   = (const float*)d_in[8];
    const float* Bias = (const float*)d_in[9];
    spatial_attn_kernel<<<dim3(NBS * NT), dim3(512), 0, stream>>>(
        X, Wq, Wk, Wkey, U, AC, Al, Wo, Bias, (float*)d_out);
}

// Round 2
// 93.170 us; speedup vs baseline: 1.2122x; 1.2122x over previous
//
#include <hip/hip_runtime.h>
#include <hip/hip_bf16.h>

#define NBS 8
#define NT 32
#define NF 128
#define NDIN 64
#define NNH 8
#define NDOUT 64

typedef __bf16 bf16_t;
typedef __bf16 bf16x8 __attribute__((ext_vector_type(8)));
typedef float f32x4 __attribute__((ext_vector_type(4)));

// ---------------- kernel 1: q/k projection ----------------
// One wave per (t,f): q[b,he] = sum_d X[b,f,t,d] * Wq[t,f,d,he], all 8 b at once.
// Wq/Wk read exactly once from HBM (vs 8x when fused per-(b,t)).
__global__ __launch_bounds__(256, 4)
void qk_project_kernel(const float* __restrict__ X,
                       const float* __restrict__ Wq,
                       const float* __restrict__ Wk,
                       float* __restrict__ q_ws,
                       float* __restrict__ k_ws)
{
    __shared__ float lx[4][8][64];   // per-wave X[b][d] tile
    const int w = threadIdx.x >> 6, lane = threadIdx.x & 63;
    const int gw = blockIdx.x * 4 + w;           // 0..4095
    const int t = gw >> 7, f = gw & 127;

    // stage X[b, f, t, :] for all 8 b (lane = (b, d-group))
    {
        const int b = lane >> 3, d8 = (lane & 7) << 3;
        const float* src = &X[(((size_t)b * NF + f) * NT + t) * NDIN + d8];
        const float4 v0 = *(const float4*)src;
        const float4 v1 = *(const float4*)(src + 4);
        *(float4*)&lx[w][b][d8]     = v0;
        *(float4*)&lx[w][b][d8 + 4] = v1;
    }
    __syncthreads();

    const int dq = lane >> 4, he = lane & 15;    // lane = dq*16 + he
    const float* wq = Wq + ((size_t)t * NF + f) * (NDIN * 16);
    const float* wk = Wk + ((size_t)t * NF + f) * (NDIN * 16);
    float qa[8] = {0,0,0,0,0,0,0,0}, ka[8] = {0,0,0,0,0,0,0,0};
    for (int d0 = 0; d0 < NDIN; d0 += 4) {
        const int d = d0 + dq;
        const float wqv = wq[d * 16 + he];       // wave reads 256 contiguous floats
        const float wkv = wk[d * 16 + he];
#pragma unroll
        for (int b = 0; b < 8; ++b) {
            const float x = lx[w][b][d];         // 16-lane broadcast, conflict-free
            qa[b] = fmaf(x, wqv, qa[b]);
            ka[b] = fmaf(x, wkv, ka[b]);
        }
    }
#pragma unroll
    for (int b = 0; b < 8; ++b) {                // reduce across dq (lane bits 4,5)
        qa[b] += __shfl_xor(qa[b], 16); qa[b] += __shfl_xor(qa[b], 32);
        ka[b] += __shfl_xor(ka[b], 16); ka[b] += __shfl_xor(ka[b], 32);
    }
    // lane (dq,he) writes b = dq and dq+4; layout [b][t][he][f]
#pragma unroll
    for (int bb = 0; bb < 2; ++bb) {
        const int b = dq + bb * 4;
        q_ws[(((size_t)b * NT + t) * 16 + he) * NF + f] = qa[b];
        k_ws[(((size_t)b * NT + t) * 16 + he) * NF + f] = ka[b];
    }
}

// ---------------- kernel 2: attention + output GEMMs ----------------
// One block per (b,t). 512 threads = 8 waves; wave w owns output rows f in [16w,16w+16).
__global__ __launch_bounds__(512, 2)
void spatial_attn_kernel(const float* __restrict__ X,
                         const float* __restrict__ q_ws,
                         const float* __restrict__ k_ws,
                         const float* __restrict__ Wkey,
                         const float* __restrict__ U,
                         const float* __restrict__ AC,
                         const float* __restrict__ Alpha,
                         const float* __restrict__ Wo,
                         const float* __restrict__ Bias,
                         float* __restrict__ Out)
{
    const int blk  = blockIdx.x;
    const int b    = blk & 7;
    const int t    = blk >> 3;
    const int tid  = threadIdx.x;
    const int w    = tid >> 6;
    const int lane = tid & 63;

    // LDS: 97280 B
    __shared__ bf16_t XT[NDIN][NF + 8];     // 17408  X^T bf16 (GEMM1 B operand)
    __shared__ float  qT[16][NF];           // 8192   q[he][f]
    __shared__ float  kT[16][NF];           // 8192   k[he][f]
    __shared__ float  uT[2][NF];            // 1024   u[e][l]
    __shared__ bf16_t Pl[NF][NF + 8];       // 34816  probs[f][l] bf16 (GEMM1 A)
    __shared__ bf16_t Vl[NF][72];           // 18432  vals_h[f][d] bf16 (GEMM2 A)
    __shared__ bf16_t WT[NDOUT][72];        // 9216   W[t,h-slab]^T [o][d] bf16 (GEMM2 B)

    // ---- stage X^T (bf16) ----
    for (int i = tid; i < NF * NDIN / 4; i += 512) {
        const int f = i >> 4, d4 = (i & 15) << 2;
        const float4 v = *(const float4*)&X[(((size_t)b * NF + f) * NT + t) * NDIN + d4];
        XT[d4 + 0][f] = (bf16_t)v.x; XT[d4 + 1][f] = (bf16_t)v.y;
        XT[d4 + 2][f] = (bf16_t)v.z; XT[d4 + 3][f] = (bf16_t)v.w;
    }
    // ---- load q/k from ws (coalesced) ----
    for (int i = tid; i < 16 * NF; i += 512) {
        const int he = i >> 7, f = i & 127;
        qT[he][f] = q_ws[(((size_t)b * NT + t) * 16 + he) * NF + f];
        kT[he][f] = k_ws[(((size_t)b * NT + t) * 16 + he) * NF + f];
    }
    if (tid < 256) {
        const int l = tid >> 1, e = tid & 1;
        uT[e][l] = U[((size_t)t * NF + l) * 2 + e];
    }
    const float alpha_t = Alpha[t];
    const float wk00 = Wkey[t * 4 + 0], wk01 = Wkey[t * 4 + 1];
    const float wk10 = Wkey[t * 4 + 2], wk11 = Wkey[t * 4 + 3];

    __syncthreads();

    f32x4 oacc[4] = { {0.f,0.f,0.f,0.f}, {0.f,0.f,0.f,0.f}, {0.f,0.f,0.f,0.f}, {0.f,0.f,0.f,0.f} };

    for (int h = 0; h < NNH; ++h) {
        // C1: stage W[t, h*64+d, o] transposed -> WT[o][d] (bf16)
        for (int i = tid; i < NDOUT * NDOUT; i += 512) {
            const int o = i & 63, d = i >> 6;
            WT[o][d] = (bf16_t)Wo[((size_t)t * 512 + h * 64 + d) * NDOUT + o];
        }
        // C2: scores + softmax -> Pl
        {
            const float v0 = -alpha_t;
            const float v1 = 2.f * alpha_t * AC[t * NNH + h];
            const float* kr0 = kT[2 * h + 0];
            const float* kr1 = kT[2 * h + 1];
            const float* qr0 = qT[2 * h + 0];
            const float* qr1 = qT[2 * h + 1];
            const float ka0 = kr0[lane],        ka1 = kr1[lane];
            const float kb0 = kr0[lane + 64],   kb1 = kr1[lane + 64];
            const float ua0 = uT[0][lane],      ua1 = uT[1][lane];
            const float ub0 = uT[0][lane + 64], ub1 = uT[1][lane + 64];
            const float la = (float)lane, lb = (float)(lane + 64);

            for (int i = 0; i < 8; ++i) {
                const int f1 = 16 * w + i, f2 = f1 + 8;
                const float q10 = qr0[f1], q11 = qr1[f1];
                const float q20 = qr0[f2], q21 = qr1[f2];
                const float kf10 = kr0[f1], kf11 = kr1[f1];
                const float kf20 = kr0[f2], kf21 = kr1[f2];
                const float c10 = (q10 + v0) * wk00 + (q11 + v1) * wk10;
                const float c11 = (q10 + v0) * wk01 + (q11 + v1) * wk11;
                const float c20 = (q20 + v0) * wk00 + (q21 + v1) * wk10;
                const float c21 = (q20 + v0) * wk01 + (q21 + v1) * wk11;
                const float d1a = la - (float)f1, d1b = lb - (float)f1;
                const float d2a = la - (float)f2, d2b = lb - (float)f2;
                float s1a = q10*ka0 + q11*ka1 + (c10*d1a + c11)*d1a + kf10*ua0 + kf11*ua1;
                float s1b = q10*kb0 + q11*kb1 + (c10*d1b + c11)*d1b + kf10*ub0 + kf11*ub1;
                float s2a = q20*ka0 + q21*ka1 + (c20*d2a + c21)*d2a + kf20*ua0 + kf21*ua1;
                float s2b = q20*kb0 + q21*kb1 + (c20*d2b + c21)*d2b + kf20*ub0 + kf21*ub1;
                float m1 = fmaxf(s1a, s1b), m2 = fmaxf(s2a, s2b);
#pragma unroll
                for (int off = 32; off > 0; off >>= 1) {
                    m1 = fmaxf(m1, __shfl_xor(m1, off));
                    m2 = fmaxf(m2, __shfl_xor(m2, off));
                }
                const float e1a = __expf(s1a - m1), e1b = __expf(s1b - m1);
                const float e2a = __expf(s2a - m2), e2b = __expf(s2b - m2);
                float t1 = e1a + e1b, t2 = e2a + e2b;
#pragma unroll
                for (int off = 32; off > 0; off >>= 1) {
                    t1 += __shfl_xor(t1, off);
                    t2 += __shfl_xor(t2, off);
                }
                const float r1 = 1.f / t1, r2 = 1.f / t2;
                Pl[f1][lane] = (bf16_t)(e1a * r1); Pl[f1][lane + 64] = (bf16_t)(e1b * r1);
                Pl[f2][lane] = (bf16_t)(e2a * r2); Pl[f2][lane + 64] = (bf16_t)(e2b * r2);
            }
        }
        __syncthreads();

        // C3: GEMM1  vals_h[16x64 per wave] = P[16x128] @ X[128x64]
        {
            f32x4 vacc[4] = { {0.f,0.f,0.f,0.f}, {0.f,0.f,0.f,0.f}, {0.f,0.f,0.f,0.f}, {0.f,0.f,0.f,0.f} };
            const int frow = 16 * w + (lane & 15);
            const int kg = (lane >> 4) << 3;
#pragma unroll
            for (int kt = 0; kt < 4; ++kt) {
                const bf16x8 a = *(const bf16x8*)&Pl[frow][kt * 32 + kg];
#pragma unroll
                for (int nt = 0; nt < 4; ++nt) {
                    const bf16x8 bb = *(const bf16x8*)&XT[nt * 16 + (lane & 15)][kt * 32 + kg];
                    vacc[nt] = __builtin_amdgcn_mfma_f32_16x16x32_bf16(a, bb, vacc[nt], 0, 0, 0);
                }
            }
            const int r0 = 16 * w + ((lane >> 4) << 2);
            const int c  = lane & 15;
#pragma unroll
            for (int nt = 0; nt < 4; ++nt)
#pragma unroll
                for (int r = 0; r < 4; ++r)
                    Vl[r0 + r][nt * 16 + c] = (bf16_t)vacc[nt][r];
        }
        __syncthreads();

        // C5: GEMM2  out[16x64 per wave] += Vl[16x64] @ Wslab[64x64]
        {
            const int frow = 16 * w + (lane & 15);
            const int kg = (lane >> 4) << 3;
#pragma unroll
            for (int kt = 0; kt < 2; ++kt) {
                const bf16x8 a = *(const bf16x8*)&Vl[frow][kt * 32 + kg];
#pragma unroll
                for (int nt = 0; nt < 4; ++nt) {
                    const bf16x8 bw = *(const bf16x8*)&WT[nt * 16 + (lane & 15)][kt * 32 + kg];
                    oacc[nt] = __builtin_amdgcn_mfma_f32_16x16x32_bf16(a, bw, oacc[nt], 0, 0, 0);
                }
            }
        }
        __syncthreads();
    }

    // ---- epilogue ----
    {
        const int r0 = 16 * w + ((lane >> 4) << 2);
        const int c  = lane & 15;
#pragma unroll
        for (int nt = 0; nt < 4; ++nt) {
#pragma unroll
            for (int r = 0; r < 4; ++r) {
                const int f = r0 + r, o = nt * 16 + c;
                Out[(((size_t)b * NF + f) * NT + t) * NDOUT + o] =
                    oacc[nt][r] + Bias[((size_t)f * NT + t) * NDOUT + o];
            }
        }
    }
}

extern "C" void kernel_launch(void* const* d_in, const int* in_sizes, int n_in,
                              void* d_out, int out_size, void* d_ws, size_t ws_size,
                              hipStream_t stream) {
    (void)in_sizes; (void)n_in; (void)ws_size; (void)out_size;
    const float* X    = (const float*)d_in[0];
    const float* Wq   = (const float*)d_in[1];
    const float* Wk   = (const float*)d_in[2];
    const float* Wkey = (const float*)d_in[3];
    const float* U    = (const float*)d_in[4];
    const float* AC   = (const float*)d_in[5];
    const float* Al   = (const float*)d_in[6];
    // d_in[7] = R is analytic (delta^2, delta), folded into score formula
    const float* Wo   = (const float*)d_in[8];
    const float* Bias = (const float*)d_in[9];

    float* q_ws = (float*)d_ws;                       // 2 MB
    float* k_ws = q_ws + (size_t)NBS * NT * 16 * NF;  // 2 MB  (total 4 MB <= ws_size)

    qk_project_kernel<<<dim3(NT * NF / 4), dim3(256), 0, stream>>>(X, Wq, Wk, q_ws, k_ws);
    spatial_attn_kernel<<<dim3(NBS * NT), dim3(512), 0, stream>>>(
        X, q_ws, k_ws, Wkey, U, AC, Al, Wo, Bias, (float*)d_out);
}

// Round 3
// 56.920 us; speedup vs baseline: 1.9842x; 1.6369x over previous
//
#include <hip/hip_runtime.h>
#include <hip/hip_bf16.h>

#define NBS 8
#define NT 32
#define NF 128
#define NDIN 64
#define NNH 8
#define NDOUT 64

typedef __bf16 bf16_t;
typedef __bf16 bf16x8 __attribute__((ext_vector_type(8)));
typedef float f32x4 __attribute__((ext_vector_type(4)));

// ---------------- kernel 1: q/k projection ----------------
// One wave per (t,f): q[b,he] = sum_d X[b,f,t,d] * Wq[t,f,d,he], all 8 b at once.
// Wq/Wk read exactly once from HBM. Memory-bound at ~42MB -> ~8us.
__global__ __launch_bounds__(256, 4)
void qk_project_kernel(const float* __restrict__ X,
                       const float* __restrict__ Wq,
                       const float* __restrict__ Wk,
                       float* __restrict__ q_ws,
                       float* __restrict__ k_ws)
{
    __shared__ float lx[4][8][64];   // per-wave X[b][d] tile
    const int w = threadIdx.x >> 6, lane = threadIdx.x & 63;
    const int gw = blockIdx.x * 4 + w;           // 0..4095
    const int t = gw >> 7, f = gw & 127;

    {
        const int b = lane >> 3, d8 = (lane & 7) << 3;
        const float* src = &X[(((size_t)b * NF + f) * NT + t) * NDIN + d8];
        const float4 v0 = *(const float4*)src;
        const float4 v1 = *(const float4*)(src + 4);
        *(float4*)&lx[w][b][d8]     = v0;
        *(float4*)&lx[w][b][d8 + 4] = v1;
    }
    __syncthreads();

    const int dq = lane >> 4, he = lane & 15;    // lane = dq*16 + he
    const float* wq = Wq + ((size_t)t * NF + f) * (NDIN * 16);
    const float* wk = Wk + ((size_t)t * NF + f) * (NDIN * 16);
    float qa[8] = {0,0,0,0,0,0,0,0}, ka[8] = {0,0,0,0,0,0,0,0};
    for (int d0 = 0; d0 < NDIN; d0 += 4) {
        const int d = d0 + dq;
        const float wqv = wq[d * 16 + he];
        const float wkv = wk[d * 16 + he];
#pragma unroll
        for (int b = 0; b < 8; ++b) {
            const float x = lx[w][b][d];
            qa[b] = fmaf(x, wqv, qa[b]);
            ka[b] = fmaf(x, wkv, ka[b]);
        }
    }
#pragma unroll
    for (int b = 0; b < 8; ++b) {
        qa[b] += __shfl_xor(qa[b], 16); qa[b] += __shfl_xor(qa[b], 32);
        ka[b] += __shfl_xor(ka[b], 16); ka[b] += __shfl_xor(ka[b], 32);
    }
#pragma unroll
    for (int bb = 0; bb < 2; ++bb) {
        const int b = dq + bb * 4;
        q_ws[(((size_t)b * NT + t) * 16 + he) * NF + f] = qa[b];
        k_ws[(((size_t)b * NT + t) * 16 + he) * NF + f] = ka[b];
    }
}

// ---------------- kernel 2: attention + output GEMMs ----------------
// One block per (b,t). 1024 threads = 16 waves (4/SIMD, 50% occupancy).
// Softmax: 8 lanes per row (r=lane>>3, s=lane&7), 16 scores/lane, 3-step reduce.
// GEMMs: wave w -> row-tile rt=w>>1, col-tiles ctb..ctb+1 (ctb=(w&1)*2).
__global__ __launch_bounds__(1024, 4)
void spatial_attn_kernel(const float* __restrict__ X,
                         const float* __restrict__ q_ws,
                         const float* __restrict__ k_ws,
                         const float* __restrict__ Wkey,
                         const float* __restrict__ U,
                         const float* __restrict__ AC,
                         const float* __restrict__ Alpha,
                         const float* __restrict__ Wo,
                         const float* __restrict__ Bias,
                         float* __restrict__ Out)
{
    const int blk  = blockIdx.x;
    const int b    = blk & 7;
    const int t    = blk >> 3;
    const int tid  = threadIdx.x;
    const int w    = tid >> 6;
    const int lane = tid & 63;

    // LDS: 113664 B
    __shared__ bf16_t XT[NDIN][NF + 8];     // 17408  X^T bf16 (GEMM1 B)
    __shared__ float  qT[16][NF];           // 8192
    __shared__ float  kT[16][NF];           // 8192
    __shared__ float4 kv[NNH][136];         // 17408  {k0,k1,u0,u1} per (h,l), swizzled p=17s+j
    __shared__ bf16_t Pl[NF][NF + 8];       // 34816  probs (GEMM1 A)
    __shared__ bf16_t Vl[NF][72];           // 18432  vals (GEMM2 A)
    __shared__ bf16_t WT[NDOUT][72];        // 9216   W slab^T (GEMM2 B)

    // ---- stage XT (bf16, transposed) ----
    for (int i = tid; i < NF * NDIN / 4; i += 1024) {
        const int f = i >> 4, d4 = (i & 15) << 2;
        const float4 v = *(const float4*)&X[(((size_t)b * NF + f) * NT + t) * NDIN + d4];
        XT[d4 + 0][f] = (bf16_t)v.x; XT[d4 + 1][f] = (bf16_t)v.y;
        XT[d4 + 2][f] = (bf16_t)v.z; XT[d4 + 3][f] = (bf16_t)v.w;
    }
    // ---- qT / kT ----
    for (int i = tid; i < 16 * NF; i += 1024) {
        const int he = i >> 7, f = i & 127;
        qT[he][f] = q_ws[(((size_t)b * NT + t) * 16 + he) * NF + f];
        kT[he][f] = k_ws[(((size_t)b * NT + t) * 16 + he) * NF + f];
    }
    // ---- kv: interleaved per-l operands, one thread per (h,l) ----
    {
        const int hh = tid >> 7, l = tid & 127;
        const float k0 = k_ws[(((size_t)b * NT + t) * 16 + 2 * hh + 0) * NF + l];
        const float k1 = k_ws[(((size_t)b * NT + t) * 16 + 2 * hh + 1) * NF + l];
        const float u0 = U[((size_t)t * NF + l) * 2 + 0];
        const float u1 = U[((size_t)t * NF + l) * 2 + 1];
        kv[hh][17 * (l >> 4) + (l & 15)] = make_float4(k0, k1, u0, u1);
    }
    const float alpha_t = Alpha[t];
    const float wk00 = Wkey[t * 4 + 0], wk01 = Wkey[t * 4 + 1];
    const float wk10 = Wkey[t * 4 + 2], wk11 = Wkey[t * 4 + 3];

    __syncthreads();

    f32x4 oacc[2] = { {0.f,0.f,0.f,0.f}, {0.f,0.f,0.f,0.f} };
    const int rt  = w >> 1;            // row tile 0..7
    const int ctb = (w & 1) << 1;      // col tiles ctb, ctb+1
    const int cq  = lane & 15;
    const int rq  = lane >> 4;

    for (int h = 0; h < NNH; ++h) {
        // C1: stage W[t, h*64+d, o]^T -> WT[o][d]  (1 float4 per thread)
        {
            const int d = tid >> 4, o4 = (tid & 15) << 2;
            const float4 v = *(const float4*)&Wo[((size_t)t * 512 + h * 64 + d) * NDOUT + o4];
            WT[o4 + 0][d] = (bf16_t)v.x; WT[o4 + 1][d] = (bf16_t)v.y;
            WT[o4 + 2][d] = (bf16_t)v.z; WT[o4 + 3][d] = (bf16_t)v.w;
        }
        // C2: scores + softmax (8 lanes per row)
        {
            const int r = lane >> 3, s = lane & 7;
            const int f = 8 * w + r;
            const float v0 = -alpha_t;
            const float v1 = 2.f * alpha_t * AC[t * NNH + h];
            const float q0  = qT[2 * h + 0][f], q1  = qT[2 * h + 1][f];
            const float kf0 = kT[2 * h + 0][f], kf1 = kT[2 * h + 1][f];
            const float c0 = (q0 + v0) * wk00 + (q1 + v1) * wk10;
            const float c1 = (q0 + v0) * wk01 + (q1 + v1) * wk11;
            const float4* kvp = &kv[h][17 * s];
            float sc[16];
            float del = (float)(s * 16 - f);
#pragma unroll
            for (int j = 0; j < 16; ++j) {
                const float4 kj = kvp[j];
                sc[j] = q0 * kj.x + q1 * kj.y + kf0 * kj.z + kf1 * kj.w
                      + (c0 * del + c1) * del;
                del += 1.f;
            }
            float m = sc[0];
#pragma unroll
            for (int j = 1; j < 16; ++j) m = fmaxf(m, sc[j]);
            m = fmaxf(m, __shfl_xor(m, 1));
            m = fmaxf(m, __shfl_xor(m, 2));
            m = fmaxf(m, __shfl_xor(m, 4));
            float sum = 0.f;
#pragma unroll
            for (int j = 0; j < 16; ++j) { sc[j] = __expf(sc[j] - m); sum += sc[j]; }
            sum += __shfl_xor(sum, 1);
            sum += __shfl_xor(sum, 2);
            sum += __shfl_xor(sum, 4);
            const float rinv = 1.f / sum;
            bf16x8 p0, p1;
#pragma unroll
            for (int j = 0; j < 8; ++j) {
                p0[j] = (bf16_t)(sc[j] * rinv);
                p1[j] = (bf16_t)(sc[j + 8] * rinv);
            }
            *(bf16x8*)&Pl[f][s * 16 + 0] = p0;
            *(bf16x8*)&Pl[f][s * 16 + 8] = p1;
        }
        __syncthreads();

        // GEMM1: V[rt-tile][ctb..ctb+1] = P[16x128] @ X[128x32-slice]
        {
            f32x4 va0 = {0.f,0.f,0.f,0.f}, va1 = {0.f,0.f,0.f,0.f};
            const int frow = rt * 16 + cq;
            const int kg = rq << 3;
#pragma unroll
            for (int kt = 0; kt < 4; ++kt) {
                const bf16x8 a  = *(const bf16x8*)&Pl[frow][kt * 32 + kg];
                const bf16x8 b0 = *(const bf16x8*)&XT[ctb * 16 + cq][kt * 32 + kg];
                const bf16x8 b1 = *(const bf16x8*)&XT[ctb * 16 + 16 + cq][kt * 32 + kg];
                va0 = __builtin_amdgcn_mfma_f32_16x16x32_bf16(a, b0, va0, 0, 0, 0);
                va1 = __builtin_amdgcn_mfma_f32_16x16x32_bf16(a, b1, va1, 0, 0, 0);
            }
            const int r0 = rt * 16 + (rq << 2);
#pragma unroll
            for (int rr = 0; rr < 4; ++rr) {
                Vl[r0 + rr][ctb * 16 + cq]      = (bf16_t)va0[rr];
                Vl[r0 + rr][ctb * 16 + 16 + cq] = (bf16_t)va1[rr];
            }
        }
        __syncthreads();

        // GEMM2: out[rt-tile][ctb..ctb+1] += V[16x64] @ Wslab[64x32-slice]
        {
            const int frow = rt * 16 + cq;
            const int kg = rq << 3;
#pragma unroll
            for (int kt = 0; kt < 2; ++kt) {
                const bf16x8 a  = *(const bf16x8*)&Vl[frow][kt * 32 + kg];
                const bf16x8 b0 = *(const bf16x8*)&WT[ctb * 16 + cq][kt * 32 + kg];
                const bf16x8 b1 = *(const bf16x8*)&WT[ctb * 16 + 16 + cq][kt * 32 + kg];
                oacc[0] = __builtin_amdgcn_mfma_f32_16x16x32_bf16(a, b0, oacc[0], 0, 0, 0);
                oacc[1] = __builtin_amdgcn_mfma_f32_16x16x32_bf16(a, b1, oacc[1], 0, 0, 0);
            }
        }
        __syncthreads();
    }

    // ---- epilogue: out = oacc + bias ----
    {
        const int r0 = rt * 16 + (rq << 2);
#pragma unroll
        for (int p = 0; p < 2; ++p) {
            const int o = (ctb + p) * 16 + cq;
#pragma unroll
            for (int rr = 0; rr < 4; ++rr) {
                const int f = r0 + rr;
                Out[(((size_t)b * NF + f) * NT + t) * NDOUT + o] =
                    oacc[p][rr] + Bias[((size_t)f * NT + t) * NDOUT + o];
            }
        }
    }
}

extern "C" void kernel_launch(void* const* d_in, const int* in_sizes, int n_in,
                              void* d_out, int out_size, void* d_ws, size_t ws_size,
                              hipStream_t stream) {
    (void)in_sizes; (void)n_in; (void)ws_size; (void)out_size;
    const float* X    = (const float*)d_in[0];
    const float* Wq   = (const float*)d_in[1];
    const float* Wk   = (const float*)d_in[2];
    const float* Wkey = (const float*)d_in[3];
    const float* U    = (const float*)d_in[4];
    const float* AC   = (const float*)d_in[5];
    const float* Al   = (const float*)d_in[6];
    // d_in[7] = R is analytic (delta^2, delta), folded into score formula
    const float* Wo   = (const float*)d_in[8];
    const float* Bias = (const float*)d_in[9];

    float* q_ws = (float*)d_ws;                       // 2 MB
    float* k_ws = q_ws + (size_t)NBS * NT * 16 * NF;  // 2 MB

    qk_project_kernel<<<dim3(NT * NF / 4), dim3(256), 0, stream>>>(X, Wq, Wk, q_ws, k_ws);
    spatial_attn_kernel<<<dim3(NBS * NT), dim3(1024), 0, stream>>>(
        X, q_ws, k_ws, Wkey, U, AC, Al, Wo, Bias, (float*)d_out);
}